// Round 3
// baseline (769.213 us; speedup 1.0000x reference)
//
#include <hip/hip_runtime.h>
#include <hip/hip_bf16.h>

#define CB 256       // batch
#define CS 200       // seq
#define CH 128       // H
#define CH2 256      // 2H
#define CL 256       // padded length
#define CPAD 56
#define CBS (CB*CS)  // 51200 tokens
#define CBL (CB*CL)  // 65536 padded rows

typedef __attribute__((ext_vector_type(8))) short bf16x8;
typedef __attribute__((ext_vector_type(4))) float f32x4;

// ---------------- static device buffers ------------------------------------
// blocked bf16 activation layout: elem(c, row) at (c>>5)*(rows*32) + row*32 + (c&31)
__device__ __hip_bfloat16 g_cat [(size_t)CBS*256]; // [ids | llm], blocked(CBS)
__device__ __hip_bfloat16 g_g1  [(size_t)CBS*256]; // blocked(CBS)
__device__ float          g_x   [(size_t)CBL*128]; // residual stream f32 row-major
__device__ __hip_bfloat16 g_xb  [(size_t)CBL*128]; // bf16 x, blocked(CBL)
__device__ __hip_bfloat16 g_h   [(size_t)CBL*512]; // [re | im], blocked(CBL)
__device__ __hip_bfloat16 g_ffh [(size_t)CBL*512]; // blocked(CBL)
__device__ float g_mask[CBL];
__device__ float g_gamma2[512];
__device__ float g_bincat[512];
__device__ float g_lre[128*CH2];
__device__ float g_lim[128*CH2];
// bf16 weight copies (row-major [N][K])
__device__ __hip_bfloat16 g_Wmap  [128*768];
__device__ __hip_bfloat16 g_Wg1   [256*256];
__device__ __hip_bfloat16 g_Wg2   [128*256];
__device__ __hip_bfloat16 g_Wincat[512*128];
__device__ __hip_bfloat16 g_Woutcat[128*512];
__device__ __hip_bfloat16 g_Wff1  [512*128];
__device__ __hip_bfloat16 g_Wff2  [128*512];

__device__ __forceinline__ __hip_bfloat16* bbuf(int s){
  switch(s){
    case 0: return g_cat;   case 1: return g_g1;
    case 3: return g_xb;    case 5: return g_h;
    case 6: return g_ffh;   case 7: return g_Wmap;  case 8: return g_Wg1;
    case 9: return g_Wg2;   case 10: return g_Wincat; case 11: return g_Woutcat;
    case 12: return g_Wff1; case 13: return g_Wff2; default: return nullptr;
  }
}

__device__ __forceinline__ short f2bf(float f){
  unsigned u = __float_as_uint(f);
  unsigned r = (u + 0x7fffu + ((u>>16)&1u)) >> 16;
  return (short)r;
}
__device__ __forceinline__ float bf2f(short s){
  return __uint_as_float(((unsigned)(unsigned short)s) << 16);
}

// ---------------- mask ------------------------------------------------------
__global__ void k_mask(const int* __restrict__ ids){
  int b = blockIdx.x, t = threadIdx.x;
  float m = 0.f;
  if (t >= CPAD) m = (ids[b*CS + (t - CPAD)] > 0) ? 1.f : 0.f;
  g_mask[b*CL + t] = m;
}

// ---------------- item-embedding gather into cat[:, :128] (blocked) --------
__global__ void k_gather_ids(const int* __restrict__ ids,
                             const float* __restrict__ item_emb){
  int tok = blockIdx.x, c = threadIdx.x;
  int id = ids[tok];
  g_cat[(size_t)(c>>5)*(CBS*32) + (size_t)tok*32 + (c&31)]
      = __float2bfloat16(item_emb[(size_t)id*128 + c]);
}

// ---------------- weight converts ------------------------------------------
__global__ void k_wcvt(const float* __restrict__ s, int dSel, long dOff, int n){
  int i = blockIdx.x*256 + threadIdx.x;
  if (i < n) bbuf(dSel)[dOff + i] = __float2bfloat16(s[i]);
}
__global__ void k_wcat_out(const float* __restrict__ wre,
                           const float* __restrict__ wim){
  int i = blockIdx.x*256 + threadIdx.x;  // 128*512
  int r = i >> 9, c = i & 511;
  float v = (c < 256) ? wre[r*256 + c] : -wim[r*256 + (c - 256)];
  g_Woutcat[i] = __float2bfloat16(v);
}

// ---------------- MFMA GEMM with optional fused epilogues -------------------
// tile 128x128, BK=32, 4 waves (2x2), 4x4 16x16x32 fragments per wave.
// EPI 0: C write (blocked). EPI 1: v+=x; LN; write x/xb. EPI 2: sigmoid-mix-LN0.
template<int ACT, int EPI, bool GATHER, bool COLSCALE, bool ABLK, bool CBLK>
__global__ __launch_bounds__(256) void k_mgemm(
    int aSel, const float* __restrict__ Af32, int ldaF,
    int wSel, int biasSel, const float* __restrict__ biasExt,
    const int* __restrict__ gidx,
    int cSel, long aBlkStride, long cBlkStride, int colOff, int K,
    const float* __restrict__ lnG, const float* __restrict__ lnB)
{
  __shared__ char lA[128*80];
  __shared__ char lB[128*80];
  const short* A = GATHER ? nullptr : (const short*)bbuf(aSel);
  const short* W = (const short*)bbuf(wSel);
  const float* bias = (biasSel == 0) ? g_bincat : biasExt;
  __hip_bfloat16* C = (EPI == 0) ? bbuf(cSel) : nullptr;

  const int t = threadIdx.x;
  const int m0 = blockIdx.x*128, n0 = blockIdx.y*128;
  const int lane = t & 63, wv = t >> 6;
  const int wr = wv >> 1, wc = wv & 1;
  const int fr = lane & 15, fq = lane >> 4;
  const int srow = t >> 2, sq = t & 3;

  f32x4 acc[4][4] = {};

  for (int k0 = 0; k0 < K; k0 += 32){
    #pragma unroll
    for (int i = 0; i < 2; i++){
      int row = srow + i*64;
      bf16x8 av;
      if (GATHER){
        long ar = gidx[m0 + row];
        const float* p = Af32 + ar*(long)ldaF + k0 + sq*8;
        float4 x0 = *(const float4*)p;
        float4 x1 = *(const float4*)(p + 4);
        av[0]=f2bf(x0.x); av[1]=f2bf(x0.y); av[2]=f2bf(x0.z); av[3]=f2bf(x0.w);
        av[4]=f2bf(x1.x); av[5]=f2bf(x1.y); av[6]=f2bf(x1.z); av[7]=f2bf(x1.w);
      } else if (ABLK){
        av = *(const bf16x8*)(A + (long)(k0>>5)*aBlkStride + (long)(m0+row)*32 + sq*8);
      } else {
        av = *(const bf16x8*)(A + (long)(m0+row)*K + k0 + sq*8);
      }
      *(bf16x8*)(lA + row*80 + sq*16) = av;
      bf16x8 wv8 = *(const bf16x8*)(W + (long)(n0+row)*K + k0 + sq*8);
      *(bf16x8*)(lB + row*80 + sq*16) = wv8;
    }
    __syncthreads();
    bf16x8 af[4], bw[4];
    #pragma unroll
    for (int m = 0; m < 4; m++)
      af[m] = *(const bf16x8*)(lA + (wr*64 + m*16 + fr)*80 + fq*16);
    #pragma unroll
    for (int n = 0; n < 4; n++)
      bw[n] = *(const bf16x8*)(lB + (wc*64 + n*16 + fr)*80 + fq*16);
    #pragma unroll
    for (int m = 0; m < 4; m++)
      #pragma unroll
      for (int n = 0; n < 4; n++)
        acc[m][n] = __builtin_amdgcn_mfma_f32_16x16x32_bf16(af[m], bw[n], acc[m][n], 0, 0, 0);
    __syncthreads();
  }

  if (EPI == 0){
    #pragma unroll
    for (int m = 0; m < 4; m++){
      #pragma unroll
      for (int j = 0; j < 4; j++){
        long row = m0 + wr*64 + m*16 + fq*4 + j;
        #pragma unroll
        for (int n = 0; n < 4; n++){
          int colL = n0 + wc*64 + n*16 + fr;
          float v = acc[m][n][j] + bias[colL];
          if (COLSCALE) v *= g_gamma2[colL];
          if (ACT == 1) v = 0.5f * v * (1.0f + erff(v * 0.70710678118654752f));
          int colS = colL + colOff;
          if (CBLK)
            ((short*)C)[(long)(colS>>5)*cBlkStride + row*32 + (colS&31)] = f2bf(v);
          else
            C[row*(long)512 + colS] = __float2bfloat16(v);
        }
      }
    }
  } else {
    // fused row-LN epilogue (requires N==128, grid.y==1: n0==0)
    float* red = (float*)lA;   // [2 wc][128 rt][2]
    #pragma unroll
    for (int m = 0; m < 4; m++){
      #pragma unroll
      for (int j = 0; j < 4; j++){
        int rt = wr*64 + m*16 + fq*4 + j;
        long xrow;
        if (EPI == 2){
          int tok = m0 + rt; int b = tok / CS; int s = tok - b*CS;
          xrow = (long)b*CL + CPAD + s;
        } else xrow = m0 + rt;
        float s1 = 0.f, s2 = 0.f;
        #pragma unroll
        for (int n = 0; n < 4; n++){
          int col = wc*64 + n*16 + fr;
          float v = acc[m][n][j] + bias[col];
          if (EPI == 2){
            v = 1.0f / (1.0f + expf(-v));
            long tok = m0 + rt;
            float idv = bf2f(((const short*)g_cat)[(long)(col>>5)*(CBS*32) + tok*32 + (col&31)]);
            float lmv = bf2f(((const short*)g_cat)[(long)((col+128)>>5)*(CBS*32) + tok*32 + (col&31)]);
            v = v*idv + (1.0f - v)*lmv;
          } else {
            v += g_x[xrow*128 + col];
          }
          acc[m][n][j] = v; s1 += v; s2 += v*v;
        }
        #pragma unroll
        for (int off = 1; off < 16; off <<= 1){
          s1 += __shfl_xor(s1, off); s2 += __shfl_xor(s2, off);
        }
        if (fr == 0){
          red[(wc*128 + rt)*2]     = s1;
          red[(wc*128 + rt)*2 + 1] = s2;
        }
      }
    }
    __syncthreads();
    #pragma unroll
    for (int m = 0; m < 4; m++){
      #pragma unroll
      for (int j = 0; j < 4; j++){
        int rt = wr*64 + m*16 + fq*4 + j;
        long xrow;
        if (EPI == 2){
          int tok = m0 + rt; int b = tok / CS; int s = tok - b*CS;
          xrow = (long)b*CL + CPAD + s;
        } else xrow = m0 + rt;
        float s1 = red[rt*2]     + red[(128+rt)*2];
        float s2 = red[rt*2 + 1] + red[(128+rt)*2 + 1];
        float mu = s1 * (1.f/128.f);
        float var = s2 * (1.f/128.f) - mu*mu;
        float rstd = rsqrtf(var + 1e-12f);
        #pragma unroll
        for (int n = 0; n < 4; n++){
          int col = wc*64 + n*16 + fr;
          float o = (acc[m][n][j] - mu)*rstd*lnG[col] + lnB[col];
          g_x[xrow*128 + col] = o;
          ((short*)g_xb)[(long)(col>>5)*((long)CBL*32) + xrow*32 + (col&31)] = f2bf(o);
        }
      }
    }
  }
}

// ---------------- zero pad rows of x ----------------------------------------
__global__ void k_zero_pad(){
  int i = blockIdx.x*256 + threadIdx.x;   // over CB*CPAD*CH
  int c = i & (CH-1);
  int r = (i >> 7) % CPAD;
  int b = i / (CPAD*CH);
  long row = (long)b*CL + r;
  g_x[row*128 + c] = 0.f;
  ((short*)g_xb)[(long)(c>>5)*((long)CBL*32) + row*32 + (c&31)] = 0;
}

// ---------------- per-layer prep -------------------------------------------
__global__ void k_prep(const float* __restrict__ pl,
                       const float* __restrict__ binre,
                       const float* __restrict__ binim, int l){
  int d = threadIdx.x; // 256
  float nu = expf(pl[(l*3+0)*CH2 + d]);
  float th = expf(pl[(l*3+1)*CH2 + d]);
  float gm = expf(pl[(l*3+2)*CH2 + d]);
  g_gamma2[d] = gm; g_gamma2[d+256] = gm;
  g_bincat[d] = binre[d]; g_bincat[d+256] = binim[d];
  float r = expf(-nu);
  float lre = r*cosf(th), limv = r*sinf(th);
  float pr = lre, pi = limv;
  for (int k = 0; k < 128; k++){
    g_lre[k*CH2 + d] = pr; g_lim[k*CH2 + d] = pi;
    float nr = pr*lre - pi*limv;
    float ni = pr*limv + pi*lre;
    pr = nr; pi = ni;
  }
}

// ---------------- blocked LRU scan (exact reference semantics) --------------
// block (chunk, b): streams contiguous 16KB re + 16KB im; scan in f32 LDS.
__global__ __launch_bounds__(256) void k_scan(){
  __shared__ float sre[CL*32];
  __shared__ float sim[CL*32];
  int b = blockIdx.y, ch = blockIdx.x;  // ch 0..7
  int tid = threadIdx.x;
  const short* Hre = (const short*)g_h + (size_t)ch*((size_t)CBL*32) + (size_t)b*CL*32;
  const short* Him = (const short*)g_h + (size_t)(ch+8)*((size_t)CBL*32) + (size_t)b*CL*32;

  for (int u = tid; u < CL*4; u += 256){
    bf16x8 r8 = ((const bf16x8*)Hre)[u];
    bf16x8 i8 = ((const bf16x8*)Him)[u];
    int base = u*8;
    #pragma unroll
    for (int k = 0; k < 8; k++){ sre[base+k] = bf2f(r8[k]); sim[base+k] = bf2f(i8[k]); }
  }
  __syncthreads();

  for (int i = 1; i <= 8; i++){
    int half = 1 << (i-1);
    for (int w = tid; w < 128*32; w += 256){
      int dl = w & 31, u = w >> 5;
      int blk = u >> (i-1), j = u & (half-1);
      int p = (blk << i) + half - 1;
      int tt = p + 1 + j;
      float mv = g_mask[b*CL + p];
      float lr = g_lre[j*CH2 + ch*32 + dl];
      float li = g_lim[j*CH2 + ch*32 + dl];
      float hr = sre[p*32 + dl], hi = sim[p*32 + dl];
      sre[tt*32 + dl] += (lr*hr - li*hi) * mv;
      sim[tt*32 + dl] += (lr*hi + li*hr) * mv;
    }
    __syncthreads();
  }

  short* Hro = (short*)g_h + (size_t)ch*((size_t)CBL*32) + (size_t)b*CL*32;
  short* Hio = (short*)g_h + (size_t)(ch+8)*((size_t)CBL*32) + (size_t)b*CL*32;
  for (int u = tid; u < CL*4; u += 256){
    int base = u*8;
    bf16x8 r8, i8;
    #pragma unroll
    for (int k = 0; k < 8; k++){ r8[k] = f2bf(sre[base+k]); i8[k] = f2bf(sim[base+k]); }
    ((bf16x8*)Hro)[u] = r8;
    ((bf16x8*)Hio)[u] = i8;
  }
}

// ---------------- final copy -----------------------------------------------
__global__ void k_copy_out(float* __restrict__ out){
  int i = blockIdx.x*256 + threadIdx.x;  // over CBS*CH
  int tok = i >> 7, c = i & (CH-1);
  int b = tok / CS, s = tok - b*CS;
  out[i] = g_x[((size_t)b*CL + CPAD + s)*CH + c];
}

// ---------------------------------------------------------------------------
extern "C" void kernel_launch(void* const* d_in, const int* in_sizes, int n_in,
                              void* d_out, int out_size, void* d_ws, size_t ws_size,
                              hipStream_t stream) {
  const int*   ids       = (const int*)  d_in[0];
  const float* item_emb  = (const float*)d_in[1];
  const float* llm_emb   = (const float*)d_in[2];
  const float* W_map     = (const float*)d_in[3];
  const float* b_map     = (const float*)d_in[4];
  const float* Wg1       = (const float*)d_in[5];
  const float* bg1       = (const float*)d_in[6];
  const float* Wg2       = (const float*)d_in[7];
  const float* bg2       = (const float*)d_in[8];
  const float* ln0_g     = (const float*)d_in[9];
  const float* ln0_b     = (const float*)d_in[10];
  const float* params_log= (const float*)d_in[11];
  const float* Win_re    = (const float*)d_in[12];
  const float* Win_im    = (const float*)d_in[13];
  const float* bin_re    = (const float*)d_in[14];
  const float* bin_im    = (const float*)d_in[15];
  const float* Wout_re   = (const float*)d_in[16];
  const float* Wout_im   = (const float*)d_in[17];
  const float* bout_re   = (const float*)d_in[18];
  const float* ln1_g     = (const float*)d_in[20];
  const float* ln1_b     = (const float*)d_in[21];
  const float* Wff1      = (const float*)d_in[22];
  const float* bff1      = (const float*)d_in[23];
  const float* Wff2      = (const float*)d_in[24];
  const float* bff2      = (const float*)d_in[25];
  const float* ln2_g     = (const float*)d_in[26];
  const float* ln2_b     = (const float*)d_in[27];
  float* out = (float*)d_out;

  dim3 blk(256);
  const long SBS = (long)CBS*32, SBL = (long)CBL*32;

  // weight converts
  k_wcvt<<<384, blk, 0, stream>>>(W_map, 7, 0, 128*768);
  k_wcvt<<<256, blk, 0, stream>>>(Wg1,   8, 0, 256*256);
  k_wcvt<<<128, blk, 0, stream>>>(Wg2,   9, 0, 128*256);

  k_mask<<<CB, CL, 0, stream>>>(ids);
  k_gather_ids<<<CBS, CH, 0, stream>>>(ids, item_emb);

  // llm = llm_emb[ids] @ W_map^T + b_map -> cat cols 128..255 (blocked)
  k_mgemm<0,0,true ,false,false,true ><<<dim3(400,1), blk, 0, stream>>>(
      -1, llm_emb, 768, 7, -1, b_map, ids, 0, 0, SBS, 128, 768, nullptr, nullptr);
  // g1 = gelu(cat @ Wg1^T + bg1)
  k_mgemm<1,0,false,false,true ,true ><<<dim3(400,2), blk, 0, stream>>>(
      0, nullptr, 0, 8, -1, bg1, nullptr, 1, SBS, SBS, 0, 256, nullptr, nullptr);
  k_zero_pad<<<(CB*CPAD*CH)/256, blk, 0, stream>>>();
  // gate GEMM + sigmoid + mix + LN0 -> x, xb
  k_mgemm<0,2,false,false,true ,false><<<dim3(400,1), blk, 0, stream>>>(
      1, nullptr, 0, 9, -1, bg2, nullptr, -1, SBS, 0, 0, 256, ln0_g, ln0_b);

  for (int l = 0; l < 2; l++){
    k_prep<<<1, CH2, 0, stream>>>(params_log, bin_re + l*256, bin_im + l*256, l);
    k_wcvt<<<128, blk, 0, stream>>>(Win_re + (size_t)l*32768, 10, 0,     32768);
    k_wcvt<<<128, blk, 0, stream>>>(Win_im + (size_t)l*32768, 10, 32768, 32768);
    k_wcat_out<<<256, blk, 0, stream>>>(Wout_re + (size_t)l*32768, Wout_im + (size_t)l*32768);
    k_wcvt<<<256, blk, 0, stream>>>(Wff1 + (size_t)l*65536, 12, 0, 65536);
    k_wcvt<<<256, blk, 0, stream>>>(Wff2 + (size_t)l*65536, 13, 0, 65536);

    // h_cat = (x @ Win_cat^T + bin_cat) * gamma_cat  (blocked out)
    k_mgemm<0,0,false,true ,true ,true ><<<dim3(512,4), blk, 0, stream>>>(
        3, nullptr, 0, 10, 0, nullptr, nullptr, 5, SBL, SBL, 0, 128, nullptr, nullptr);

    k_scan<<<dim3(8, CB), blk, 0, stream>>>();

    // x = LN(h_cat @ Wout_cat^T + bout + x)
    k_mgemm<0,1,false,false,true ,false><<<dim3(512,1), blk, 0, stream>>>(
        5, nullptr, 0, 11, -1, bout_re + l*128, nullptr, -1, SBL, 0, 0, 512,
        ln1_g + l*128, ln1_b + l*128);

    // ffh = gelu(x @ Wff1^T + bff1)
    k_mgemm<1,0,false,false,true ,true ><<<dim3(512,4), blk, 0, stream>>>(
        3, nullptr, 0, 12, -1, bff1 + l*512, nullptr, 6, SBL, SBL, 0, 128, nullptr, nullptr);
    // x = LN(ffh @ Wff2^T + bff2 + x)
    k_mgemm<0,1,false,false,true ,false><<<dim3(512,1), blk, 0, stream>>>(
        6, nullptr, 0, 13, -1, bff2 + l*128, nullptr, -1, SBL, 0, 0, 512,
        ln2_g + l*128, ln2_b + l*128);
  }

  k_copy_out<<<(CBS*CH)/256, blk, 0, stream>>>(out);
}

// Round 4
// 616.836 us; speedup vs baseline: 1.2470x; 1.2470x over previous
//
#include <hip/hip_runtime.h>
#include <hip/hip_bf16.h>

#define CB 256       // batch
#define CS 200       // seq
#define CH 128       // H
#define CH2 256      // 2H
#define CL 256       // padded length
#define CPAD 56
#define CBS (CB*CS)  // 51200 tokens
#define CBL (CB*CL)  // 65536 padded rows

typedef __attribute__((ext_vector_type(8))) short bf16x8;
typedef __attribute__((ext_vector_type(4))) float f32x4;

#define SB16S ((long)CBS*16)   // 16-chunk stride, token buffers
#define SB16L ((long)CBL*16)   // 16-chunk stride, padded buffers

// ---------------- static device buffers ------------------------------------
// blocked bf16 activations: elem(c,row) at (c>>4)*(rows*16) + row*16 + (c&15)
__device__ __hip_bfloat16 g_cat [(size_t)CBS*256];
__device__ __hip_bfloat16 g_g1  [(size_t)CBS*256];
__device__ float          g_x   [(size_t)CBL*128]; // f32 residual, row-major
__device__ __hip_bfloat16 g_xb  [(size_t)CBL*128]; // bf16 x, blocked
__device__ __hip_bfloat16 g_h   [(size_t)CBL*512]; // [re|im], blocked
__device__ __hip_bfloat16 g_ffh [(size_t)CBL*512]; // blocked
__device__ float g_mask[CBL];
__device__ float g_gamma2[2*512];
__device__ float g_bincat[2*512];
__device__ float2 g_lam[2*16*128*16];  // [l][ch16][j][dl] -> (re,im) of lambda^{j+1}
// bf16 weights, 16-K-chunk blocked: elem(r,c) at (c>>4)*(N*16) + r*16 + (c&15)
__device__ __hip_bfloat16 g_Wmap  [128*768];
__device__ __hip_bfloat16 g_Wg1   [256*256];
__device__ __hip_bfloat16 g_Wg2   [128*256];
__device__ __hip_bfloat16 g_Wincat[2*512*128];
__device__ __hip_bfloat16 g_Woutcat[2*128*512];
__device__ __hip_bfloat16 g_Wff1  [2*512*128];
__device__ __hip_bfloat16 g_Wff2  [2*128*512];

__device__ __forceinline__ short f2bf(float f){
  unsigned u = __float_as_uint(f);
  unsigned r = (u + 0x7fffu + ((u>>16)&1u)) >> 16;
  return (short)r;
}
__device__ __forceinline__ float bf2f(short s){
  return __uint_as_float(((unsigned)(unsigned short)s) << 16);
}

// ---------------- mask ------------------------------------------------------
__global__ void k_mask(const int* __restrict__ ids){
  int b = blockIdx.x, t = threadIdx.x;
  float m = 0.f;
  if (t >= CPAD) m = (ids[b*CS + (t - CPAD)] > 0) ? 1.f : 0.f;
  g_mask[b*CL + t] = m;
}

// ---------------- item-embedding gather (blocked-16) ------------------------
__global__ void k_gather_ids(const int* __restrict__ ids,
                             const float* __restrict__ item_emb){
  int tok = blockIdx.x, c = threadIdx.x;
  int id = ids[tok];
  ((short*)g_cat)[(long)(c>>4)*SB16S + (long)tok*16 + (c&15)]
      = f2bf(item_emb[(size_t)id*128 + c]);
}

// ---------------- one-shot weight convert + block -----------------------------
__device__ __forceinline__ void wblk(__hip_bfloat16* dst, int N, int K, int i, float v){
  int r = i / K, c = i - r*K;
  ((short*)dst)[(long)(c>>4)*((long)N*16) + (long)r*16 + (c&15)] = f2bf(v);
}
__global__ void k_wcvt_all(const float* __restrict__ W_map, const float* __restrict__ Wg1,
                           const float* __restrict__ Wg2,
                           const float* __restrict__ Win_re, const float* __restrict__ Win_im,
                           const float* __restrict__ Wout_re, const float* __restrict__ Wout_im,
                           const float* __restrict__ Wff1, const float* __restrict__ Wff2){
  int i = blockIdx.x*256 + threadIdx.x;
  if (i < 98304){ wblk(g_Wmap, 128, 768, i, W_map[i]); return; }
  i -= 98304;
  if (i < 65536){ wblk(g_Wg1, 256, 256, i, Wg1[i]); return; }
  i -= 65536;
  if (i < 32768){ wblk(g_Wg2, 128, 256, i, Wg2[i]); return; }
  i -= 32768;
  int l = i / 262144; i -= l*262144;
  __hip_bfloat16* base;
  if (i < 32768){ wblk(g_Wincat + (long)l*65536, 512, 128, i,       Win_re[(long)l*32768 + i]); return; }
  i -= 32768;
  if (i < 32768){ wblk(g_Wincat + (long)l*65536, 512, 128, i+32768, Win_im[(long)l*32768 + i]); return; }
  i -= 32768;
  if (i < 65536){
    int r = i >> 9, c = i & 511;
    float v = (c < 256) ? Wout_re[(long)l*32768 + r*256 + c]
                        : -Wout_im[(long)l*32768 + r*256 + (c-256)];
    wblk(g_Woutcat + (long)l*65536, 128, 512, i, v); return;
  }
  i -= 65536;
  if (i < 65536){ wblk(g_Wff1 + (long)l*65536, 512, 128, i, Wff1[(long)l*65536 + i]); return; }
  i -= 65536;
  wblk(g_Wff2 + (long)l*65536, 128, 512, i, Wff2[(long)l*65536 + i]);
}

// ---------------- per-layer prep (both layers, 1 launch) --------------------
__global__ void k_prep(const float* __restrict__ pl,
                       const float* __restrict__ binre,
                       const float* __restrict__ binim){
  int l = blockIdx.x, d = threadIdx.x; // 2 x 256
  float nu = expf(pl[(l*3+0)*CH2 + d]);
  float th = expf(pl[(l*3+1)*CH2 + d]);
  float gm = expf(pl[(l*3+2)*CH2 + d]);
  g_gamma2[l*512 + d] = gm;       g_gamma2[l*512 + d + 256] = gm;
  g_bincat[l*512 + d] = binre[l*256 + d];
  g_bincat[l*512 + d + 256] = binim[l*256 + d];
  float r = expf(-nu);
  float lre = r*cosf(th), lim = r*sinf(th);
  float pr = lre, pi = lim;
  long base = ((long)l*16 + (d>>4))*2048 + (d&15);
  for (int k = 0; k < 128; k++){
    g_lam[base + (long)k*16] = make_float2(pr, pi);
    float nr = pr*lre - pi*lim;
    float ni = pr*lim + pi*lre;
    pr = nr; pi = ni;
  }
}

// ---------------- MFMA GEMM body --------------------------------------------
// tile 128x128, BK=32, 4 waves. EPI0: 2x2 waves, blocked C write.
// EPI1: 4x1 waves, LN(v + x) -> x/xb.  EPI2: 4x1, sigmoid-mix-LN0 -> x/xb.
template<int ACT, int EPI, bool GATHER, bool COLSCALE>
__device__ __forceinline__ void mgemm_body(
    const short* __restrict__ A, const float* __restrict__ Af32, int ldaF,
    const short* __restrict__ W, long wBlkStride,
    const float* __restrict__ bias, const float* __restrict__ gamma,
    const int* __restrict__ gidx, short* __restrict__ C,
    long aBlkStride, long cBlkStride, int colOff, int K,
    const float* __restrict__ lnG, const float* __restrict__ lnB)
{
  __shared__ __align__(16) char lA[128*80];
  __shared__ __align__(16) char lB[128*80];
  constexpr int MF = (EPI==0)?4:2;
  constexpr int NF = (EPI==0)?4:8;
  const int t = threadIdx.x;
  const int m0 = blockIdx.x*128, n0 = blockIdx.y*128;
  const int lane = t & 63, wv = t >> 6;
  const int wr = (EPI==0)?(wv>>1):wv;
  const int wc = (EPI==0)?(wv&1):0;
  const int fr = lane & 15, fq = lane >> 4;
  const int srow = t >> 2, sq = t & 3;
  const int rowB = wr*(MF*16), colB = wc*64;

  f32x4 acc[MF][NF] = {};

  for (int k0 = 0; k0 < K; k0 += 32){
    #pragma unroll
    for (int i = 0; i < 2; i++){
      int row = srow + i*64;
      int c = k0 + sq*8;
      bf16x8 av;
      if (GATHER){
        long ar = gidx[m0 + row];
        const float* p = Af32 + ar*(long)ldaF + c;
        float4 x0 = *(const float4*)p;
        float4 x1 = *(const float4*)(p + 4);
        av[0]=f2bf(x0.x); av[1]=f2bf(x0.y); av[2]=f2bf(x0.z); av[3]=f2bf(x0.w);
        av[4]=f2bf(x1.x); av[5]=f2bf(x1.y); av[6]=f2bf(x1.z); av[7]=f2bf(x1.w);
      } else {
        av = *(const bf16x8*)(A + (long)(c>>4)*aBlkStride + (long)(m0+row)*16 + (c&15));
      }
      *(bf16x8*)(lA + row*80 + sq*16) = av;
      bf16x8 wv8 = *(const bf16x8*)(W + (long)(c>>4)*wBlkStride + (long)(n0+row)*16 + (c&15));
      *(bf16x8*)(lB + row*80 + sq*16) = wv8;
    }
    __syncthreads();
    bf16x8 af[MF], bw[NF];
    #pragma unroll
    for (int m = 0; m < MF; m++)
      af[m] = *(const bf16x8*)(lA + (rowB + m*16 + fr)*80 + fq*16);
    #pragma unroll
    for (int n = 0; n < NF; n++)
      bw[n] = *(const bf16x8*)(lB + (colB + n*16 + fr)*80 + fq*16);
    #pragma unroll
    for (int m = 0; m < MF; m++)
      #pragma unroll
      for (int n = 0; n < NF; n++)
        acc[m][n] = __builtin_amdgcn_mfma_f32_16x16x32_bf16(af[m], bw[n], acc[m][n], 0, 0, 0);
    __syncthreads();
  }

  if (EPI == 0){
    #pragma unroll
    for (int m = 0; m < MF; m++){
      #pragma unroll
      for (int j = 0; j < 4; j++){
        long row = m0 + rowB + m*16 + fq*4 + j;
        #pragma unroll
        for (int n = 0; n < NF; n++){
          int colL = n0 + colB + n*16 + fr;
          float v = acc[m][n][j] + bias[colL];
          if (COLSCALE) v *= gamma[colL];
          if (ACT == 1) v = 0.5f * v * (1.0f + erff(v * 0.70710678118654752f));
          int colS = colL + colOff;
          C[(long)(colS>>4)*cBlkStride + row*16 + (colS&15)] = f2bf(v);
        }
      }
    }
  } else {
    #pragma unroll
    for (int m = 0; m < MF; m++){
      #pragma unroll
      for (int j = 0; j < 4; j++){
        int rt = rowB + m*16 + fq*4 + j;
        int tok = m0 + rt;
        long xrow;
        if (EPI == 2){ int b = tok / CS; int s = tok - b*CS; xrow = (long)b*CL + CPAD + s; }
        else xrow = tok;
        float vv[NF];
        float s1 = 0.f, s2 = 0.f;
        #pragma unroll
        for (int n = 0; n < NF; n++){
          int col = n*16 + fr;
          float v = acc[m][n][j] + bias[col];
          if (EPI == 2){
            v = 1.0f / (1.0f + expf(-v));
            float idv = bf2f(((const short*)g_cat)[(long)n*SB16S + (long)tok*16 + fr]);
            float lmv = bf2f(((const short*)g_cat)[(long)(n+8)*SB16S + (long)tok*16 + fr]);
            v = v*idv + (1.0f - v)*lmv;
          } else {
            v += g_x[xrow*128 + col];
          }
          vv[n] = v; s1 += v; s2 += v*v;
        }
        #pragma unroll
        for (int off = 1; off < 16; off <<= 1){
          s1 += __shfl_xor(s1, off); s2 += __shfl_xor(s2, off);
        }
        float mu = s1 * (1.f/128.f);
        float var = s2 * (1.f/128.f) - mu*mu;
        float rstd = rsqrtf(var + 1e-12f);
        #pragma unroll
        for (int n = 0; n < NF; n++){
          int col = n*16 + fr;
          float o = (vv[n] - mu)*rstd*lnG[col] + lnB[col];
          g_x[xrow*128 + col] = o;
          ((short*)g_xb)[(long)n*SB16L + xrow*16 + fr] = f2bf(o);
        }
      }
    }
  }
}

// ---------------- named GEMM wrappers ---------------------------------------
__global__ __launch_bounds__(256) void kg_llm(const float* llm_emb, const float* b_map, const int* ids){
  mgemm_body<0,0,true,false>(nullptr, llm_emb, 768, (const short*)g_Wmap, 128L*16,
                             b_map, nullptr, ids, (short*)g_cat, 0, SB16S, 128, 768, nullptr, nullptr);
}
__global__ __launch_bounds__(256) void kg_g1(const float* bg1){
  mgemm_body<1,0,false,false>((const short*)g_cat, nullptr, 0, (const short*)g_Wg1, 256L*16,
                              bg1, nullptr, nullptr, (short*)g_g1, SB16S, SB16S, 0, 256, nullptr, nullptr);
}
__global__ __launch_bounds__(256) void kg_gate(const float* bg2, const float* ln0g, const float* ln0b){
  mgemm_body<0,2,false,false>((const short*)g_g1, nullptr, 0, (const short*)g_Wg2, 128L*16,
                              bg2, nullptr, nullptr, nullptr, SB16S, 0, 0, 256, ln0g, ln0b);
}
__global__ __launch_bounds__(256) void kg_h(int l){
  mgemm_body<0,0,false,true>((const short*)g_xb, nullptr, 0,
                             (const short*)g_Wincat + (long)l*65536, 512L*16,
                             g_bincat + l*512, g_gamma2 + l*512, nullptr, (short*)g_h,
                             SB16L, SB16L, 0, 128, nullptr, nullptr);
}
__global__ __launch_bounds__(256) void kg_out(int l, const float* bout, const float* g, const float* b){
  mgemm_body<0,1,false,false>((const short*)g_h, nullptr, 0,
                              (const short*)g_Woutcat + (long)l*65536, 128L*16,
                              bout, nullptr, nullptr, nullptr, SB16L, 0, 0, 512, g, b);
}
__global__ __launch_bounds__(256) void kg_ff1(int l, const float* bff1){
  mgemm_body<1,0,false,false>((const short*)g_xb, nullptr, 0,
                              (const short*)g_Wff1 + (long)l*65536, 512L*16,
                              bff1, nullptr, nullptr, (short*)g_ffh, SB16L, SB16L, 0, 128, nullptr, nullptr);
}
__global__ __launch_bounds__(256) void kg_ff2(int l, const float* bff2, const float* g, const float* b){
  mgemm_body<0,1,false,false>((const short*)g_ffh, nullptr, 0,
                              (const short*)g_Wff2 + (long)l*65536, 128L*16,
                              bff2, nullptr, nullptr, nullptr, SB16L, 0, 0, 512, g, b);
}

// ---------------- zero pad rows of x ----------------------------------------
__global__ void k_zero_pad(){
  int i = blockIdx.x*256 + threadIdx.x;   // over CB*CPAD*CH
  int c = i & (CH-1);
  int r = (i >> 7) % CPAD;
  int b = i / (CPAD*CH);
  long row = (long)b*CL + r;
  g_x[row*128 + c] = 0.f;
  ((short*)g_xb)[(long)(c>>4)*SB16L + row*16 + (c&15)] = 0;
}

// ---------------- blocked LRU scan (16-ch chunks, 33 KiB LDS) ---------------
__global__ __launch_bounds__(256) void k_scan(int l){
  __shared__ __align__(16) float sre[CL*16];
  __shared__ __align__(16) float sim[CL*16];
  __shared__ float smask[CL];
  int b = blockIdx.y, ch = blockIdx.x;  // ch 0..15
  int tid = threadIdx.x;
  short* Hre = (short*)g_h + (long)ch*SB16L + (long)b*CL*16;
  short* Him = (short*)g_h + (long)(ch+16)*SB16L + (long)b*CL*16;
  smask[tid] = g_mask[b*CL + tid];
  for (int q = tid; q < CL*4; q += 256){
    short4 r4 = ((const short4*)Hre)[q];
    short4 i4 = ((const short4*)Him)[q];
    ((float4*)sre)[q] = make_float4(bf2f(r4.x), bf2f(r4.y), bf2f(r4.z), bf2f(r4.w));
    ((float4*)sim)[q] = make_float4(bf2f(i4.x), bf2f(i4.y), bf2f(i4.z), bf2f(i4.w));
  }
  __syncthreads();
  const float2* lam = g_lam + ((long)l*16 + ch)*2048;
  const int dl = tid & 15, u0 = tid >> 4;
  for (int i = 1; i <= 8; i++){
    int hl = 1 << (i-1);
    #pragma unroll
    for (int k = 0; k < 8; k++){
      int u = u0 + k*16;
      int blkI = u >> (i-1), j = u & (hl-1);
      int p = (blkI << i) + hl - 1;
      int tt = p + 1 + j;
      float mv = smask[p];
      float2 L = lam[j*16 + dl];
      float hr = sre[p*16+dl], hi = sim[p*16+dl];
      sre[tt*16+dl] += (L.x*hr - L.y*hi) * mv;
      sim[tt*16+dl] += (L.x*hi + L.y*hr) * mv;
    }
    __syncthreads();
  }
  for (int q = tid; q < CL*4; q += 256){
    float4 rf = ((const float4*)sre)[q];
    float4 gf = ((const float4*)sim)[q];
    ((short4*)Hre)[q] = make_short4(f2bf(rf.x), f2bf(rf.y), f2bf(rf.z), f2bf(rf.w));
    ((short4*)Him)[q] = make_short4(f2bf(gf.x), f2bf(gf.y), f2bf(gf.z), f2bf(gf.w));
  }
}

// ---------------- final copy -----------------------------------------------
__global__ void k_copy_out(float* __restrict__ out){
  int i = blockIdx.x*256 + threadIdx.x;  // over CBS*CH
  int tok = i >> 7, c = i & (CH-1);
  int b = tok / CS, s = tok - b*CS;
  out[i] = g_x[((size_t)b*CL + CPAD + s)*CH + c];
}

// ---------------------------------------------------------------------------
extern "C" void kernel_launch(void* const* d_in, const int* in_sizes, int n_in,
                              void* d_out, int out_size, void* d_ws, size_t ws_size,
                              hipStream_t stream) {
  const int*   ids       = (const int*)  d_in[0];
  const float* item_emb  = (const float*)d_in[1];
  const float* llm_emb   = (const float*)d_in[2];
  const float* W_map     = (const float*)d_in[3];
  const float* b_map     = (const float*)d_in[4];
  const float* Wg1       = (const float*)d_in[5];
  const float* bg1       = (const float*)d_in[6];
  const float* Wg2       = (const float*)d_in[7];
  const float* bg2       = (const float*)d_in[8];
  const float* ln0_g     = (const float*)d_in[9];
  const float* ln0_b     = (const float*)d_in[10];
  const float* params_log= (const float*)d_in[11];
  const float* Win_re    = (const float*)d_in[12];
  const float* Win_im    = (const float*)d_in[13];
  const float* bin_re    = (const float*)d_in[14];
  const float* bin_im    = (const float*)d_in[15];
  const float* Wout_re   = (const float*)d_in[16];
  const float* Wout_im   = (const float*)d_in[17];
  const float* bout_re   = (const float*)d_in[18];
  const float* ln1_g     = (const float*)d_in[20];
  const float* ln1_b     = (const float*)d_in[21];
  const float* Wff1      = (const float*)d_in[22];
  const float* bff1      = (const float*)d_in[23];
  const float* Wff2      = (const float*)d_in[24];
  const float* bff2      = (const float*)d_in[25];
  const float* ln2_g     = (const float*)d_in[26];
  const float* ln2_b     = (const float*)d_in[27];
  float* out = (float*)d_out;

  dim3 blk(256);

  k_wcvt_all<<<2816, blk, 0, stream>>>(W_map, Wg1, Wg2, Win_re, Win_im,
                                       Wout_re, Wout_im, Wff1, Wff2);
  k_prep<<<2, 256, 0, stream>>>(params_log, bin_re, bin_im);
  k_mask<<<CB, CL, 0, stream>>>(ids);
  k_gather_ids<<<CBS, CH, 0, stream>>>(ids, item_emb);

  kg_llm<<<dim3(400,1), blk, 0, stream>>>(llm_emb, b_map, ids);
  kg_g1 <<<dim3(400,2), blk, 0, stream>>>(bg1);
  k_zero_pad<<<(CB*CPAD*CH)/256, blk, 0, stream>>>();
  kg_gate<<<dim3(400,1), blk, 0, stream>>>(bg2, ln0_g, ln0_b);

  for (int l = 0; l < 2; l++){
    kg_h  <<<dim3(512,4), blk, 0, stream>>>(l);
    k_scan<<<dim3(16,CB), blk, 0, stream>>>(l);
    kg_out<<<dim3(512,1), blk, 0, stream>>>(l, bout_re + l*128, ln1_g + l*128, ln1_b + l*128);
    kg_ff1<<<dim3(512,4), blk, 0, stream>>>(l, bff1 + l*512);
    kg_ff2<<<dim3(512,1), blk, 0, stream>>>(l, bff2 + l*128, ln2_g + l*128, ln2_b + l*128);
  }

  k_copy_out<<<(CBS*CH)/256, blk, 0, stream>>>(out);
}

// Round 5
// 440.340 us; speedup vs baseline: 1.7469x; 1.4008x over previous
//
#include <hip/hip_runtime.h>
#include <hip/hip_bf16.h>

#define CB 256       // batch
#define CS 200       // seq
#define CH 128       // H
#define CH2 256      // 2H
#define CL 256       // padded scan length
#define CPAD 56
#define CBS (CB*CS)  // 51200 real tokens

typedef __attribute__((ext_vector_type(8))) short bf16x8;
typedef __attribute__((ext_vector_type(4))) float f32x4;

#define SB16 ((long)CBS*16)   // 16-channel chunk stride (token-major)

// ---------------- static device buffers ------------------------------------
// blocked bf16 activations: elem(c,tok) at (c>>4)*SB16 + tok*16 + (c&15)
__device__ __align__(16) __hip_bfloat16 g_cat [(size_t)CBS*256];
__device__ __align__(16) __hip_bfloat16 g_g1  [(size_t)CBS*256];
__device__ __align__(16) __hip_bfloat16 g_xb  [(size_t)CBS*128]; // residual (bf16 only)
__device__ __align__(16) __hip_bfloat16 g_h   [(size_t)CBS*512]; // [re|im]
__device__ __align__(16) __hip_bfloat16 g_ffh [(size_t)CBS*512];
__device__ float g_mask[CB*CL];
__device__ float g_gamma2[2*512];
__device__ float g_bincat[2*512];
__device__ float2 g_lam[2*16*128*16];  // [l][ch16][j][dl]
// bf16 weights, 16-K-chunk blocked: elem(r,c) at (c>>4)*(N*16) + r*16 + (c&15)
__device__ __align__(16) __hip_bfloat16 g_Wmap  [128*768];
__device__ __align__(16) __hip_bfloat16 g_Wg1   [256*256];
__device__ __align__(16) __hip_bfloat16 g_Wg2   [128*256];
__device__ __align__(16) __hip_bfloat16 g_Wincat[2*512*128];
__device__ __align__(16) __hip_bfloat16 g_Woutcat[2*128*512];
__device__ __align__(16) __hip_bfloat16 g_Wff1  [2*512*128];
__device__ __align__(16) __hip_bfloat16 g_Wff2  [2*128*512];

__device__ __forceinline__ short f2bf(float f){
  unsigned u = __float_as_uint(f);
  unsigned r = (u + 0x7fffu + ((u>>16)&1u)) >> 16;
  return (short)r;
}
__device__ __forceinline__ float bf2f(short s){
  return __uint_as_float(((unsigned)(unsigned short)s) << 16);
}

typedef const __attribute__((address_space(1))) void* gas1;
typedef __attribute__((address_space(3))) void* las3;
__device__ __forceinline__ void gl16(const void* g, void* l){
  __builtin_amdgcn_global_load_lds((gas1)g, (las3)l, 16, 0, 0);
}

// ---------------- mask ------------------------------------------------------
__global__ void k_mask(const int* __restrict__ ids){
  int b = blockIdx.x, t = threadIdx.x;
  float m = 0.f;
  if (t >= CPAD) m = (ids[b*CS + (t - CPAD)] > 0) ? 1.f : 0.f;
  g_mask[b*CL + t] = m;
}

// ---------------- item-embedding gather (blocked-16) ------------------------
__global__ void k_gather_ids(const int* __restrict__ ids,
                             const float* __restrict__ item_emb){
  int tok = blockIdx.x, c = threadIdx.x;
  int id = ids[tok];
  ((short*)g_cat)[(long)(c>>4)*SB16 + (long)tok*16 + (c&15)]
      = f2bf(item_emb[(size_t)id*128 + c]);
}

// ---------------- one-shot weight convert + block ---------------------------
__device__ __forceinline__ void wblk(__hip_bfloat16* dst, int N, int K, int i, float v){
  int r = i / K, c = i - r*K;
  ((short*)dst)[(long)(c>>4)*((long)N*16) + (long)r*16 + (c&15)] = f2bf(v);
}
__global__ void k_wcvt_all(const float* __restrict__ W_map, const float* __restrict__ Wg1,
                           const float* __restrict__ Wg2,
                           const float* __restrict__ Win_re, const float* __restrict__ Win_im,
                           const float* __restrict__ Wout_re, const float* __restrict__ Wout_im,
                           const float* __restrict__ Wff1, const float* __restrict__ Wff2){
  int i = blockIdx.x*256 + threadIdx.x;
  if (i < 98304){ wblk(g_Wmap, 128, 768, i, W_map[i]); return; }
  i -= 98304;
  if (i < 65536){ wblk(g_Wg1, 256, 256, i, Wg1[i]); return; }
  i -= 65536;
  if (i < 32768){ wblk(g_Wg2, 128, 256, i, Wg2[i]); return; }
  i -= 32768;
  int l = i / 262144; i -= l*262144;
  if (i < 32768){ wblk(g_Wincat + (long)l*65536, 512, 128, i,       Win_re[(long)l*32768 + i]); return; }
  i -= 32768;
  if (i < 32768){ wblk(g_Wincat + (long)l*65536, 512, 128, i+32768, Win_im[(long)l*32768 + i]); return; }
  i -= 32768;
  if (i < 65536){
    int r = i >> 9, c = i & 511;
    float v = (c < 256) ? Wout_re[(long)l*32768 + r*256 + c]
                        : -Wout_im[(long)l*32768 + r*256 + (c-256)];
    wblk(g_Woutcat + (long)l*65536, 128, 512, i, v); return;
  }
  i -= 65536;
  if (i < 65536){ wblk(g_Wff1 + (long)l*65536, 512, 128, i, Wff1[(long)l*65536 + i]); return; }
  i -= 65536;
  wblk(g_Wff2 + (long)l*65536, 128, 512, i, Wff2[(long)l*65536 + i]);
}

// ---------------- per-layer prep -------------------------------------------
__global__ void k_prep(const float* __restrict__ pl,
                       const float* __restrict__ binre,
                       const float* __restrict__ binim){
  int l = blockIdx.x, d = threadIdx.x; // 2 x 256
  float nu = expf(pl[(l*3+0)*CH2 + d]);
  float th = expf(pl[(l*3+1)*CH2 + d]);
  float gm = expf(pl[(l*3+2)*CH2 + d]);
  g_gamma2[l*512 + d] = gm;       g_gamma2[l*512 + d + 256] = gm;
  g_bincat[l*512 + d] = binre[l*256 + d];
  g_bincat[l*512 + d + 256] = binim[l*256 + d];
  float r = expf(-nu);
  float lre = r*cosf(th), lim = r*sinf(th);
  float pr = lre, pi = lim;
  long base = ((long)l*16 + (d>>4))*2048 + (d&15);
  for (int k = 0; k < 128; k++){
    g_lam[base + (long)k*16] = make_float2(pr, pi);
    float nr = pr*lre - pi*lim;
    float ni = pr*lim + pi*lre;
    pr = nr; pi = ni;
  }
}

// ---------------- MFMA GEMM body, BK=64, global_load_lds staging ------------
// LDS: [4 chunks][128 rows][16 elems] bf16, linear (16KB each operand).
// EPI0: 2x2 waves (MF=4,NF=4), blocked C write.
// EPI1: 4x1 waves (MF=2,NF=8), LN(v + bias + xb) -> xb.
// EPI2: 4x1, sigmoid-mix-LN0 -> xb.
template<int ACT, int EPI, bool GATHER, bool COLSCALE>
__device__ __forceinline__ void mgemm_body(
    const short* __restrict__ A, const float* __restrict__ Af32, int ldaF,
    const short* __restrict__ W, long wBlkStride,
    const float* __restrict__ bias, const float* __restrict__ gamma,
    const int* __restrict__ gidx, short* __restrict__ C,
    long aBlkStride, int colOff, int K,
    const float* __restrict__ lnG, const float* __restrict__ lnB)
{
  __shared__ __align__(16) char lA[16384];
  __shared__ __align__(16) char lB[16384];
  constexpr int MF = (EPI==0)?4:2;
  constexpr int NF = (EPI==0)?4:8;
  const int t = threadIdx.x;
  const int m0 = blockIdx.x*128, n0 = blockIdx.y*128;
  const int lane = t & 63, wv = t >> 6;
  const int wr = (EPI==0)?(wv>>1):wv;
  const int wc = (EPI==0)?(wv&1):0;
  const int fr = lane & 15, fq = lane >> 4;
  const int rowB = wr*(MF*16), colB = wc*64;

  long gr = 0;
  if (GATHER) gr = gidx[m0 + (t>>1)];

  f32x4 acc[MF][NF] = {};

  for (int k0 = 0; k0 < K; k0 += 64){
    if (GATHER){
      int row = t>>1, half = t&1;
      #pragma unroll
      for (int cc = 0; cc < 4; cc++){
        const float* p = Af32 + gr*(long)ldaF + k0 + cc*16 + half*8;
        float4 x0 = *(const float4*)p;
        float4 x1 = *(const float4*)(p + 4);
        bf16x8 v;
        v[0]=f2bf(x0.x); v[1]=f2bf(x0.y); v[2]=f2bf(x0.z); v[3]=f2bf(x0.w);
        v[4]=f2bf(x1.x); v[5]=f2bf(x1.y); v[6]=f2bf(x1.z); v[7]=f2bf(x1.w);
        *(bf16x8*)(lA + cc*4096 + row*32 + half*16) = v;
      }
    } else {
      #pragma unroll
      for (int cc = 0; cc < 4; cc++){
        const short* gp = A + (long)((k0>>4)+cc)*aBlkStride + (long)(m0 + wv*32)*16 + (lane<<3);
        gl16(gp, lA + cc*4096 + wv*1024);
      }
    }
    #pragma unroll
    for (int cc = 0; cc < 4; cc++){
      const short* gp = W + (long)((k0>>4)+cc)*wBlkStride + (long)(n0 + wv*32)*16 + (lane<<3);
      gl16(gp, lB + cc*4096 + wv*1024);
    }
    __syncthreads();
    #pragma unroll
    for (int s = 0; s < 2; s++){
      bf16x8 af[MF], bw[NF];
      #pragma unroll
      for (int m = 0; m < MF; m++)
        af[m] = *(const bf16x8*)(lA + (s*2+(fq>>1))*4096 + (rowB + m*16 + fr)*32 + (fq&1)*16);
      #pragma unroll
      for (int n = 0; n < NF; n++)
        bw[n] = *(const bf16x8*)(lB + (s*2+(fq>>1))*4096 + (colB + n*16 + fr)*32 + (fq&1)*16);
      #pragma unroll
      for (int m = 0; m < MF; m++)
        #pragma unroll
        for (int n = 0; n < NF; n++)
          acc[m][n] = __builtin_amdgcn_mfma_f32_16x16x32_bf16(af[m], bw[n], acc[m][n], 0, 0, 0);
    }
    __syncthreads();
  }

  if (EPI == 0){
    #pragma unroll
    for (int m = 0; m < MF; m++){
      #pragma unroll
      for (int j = 0; j < 4; j++){
        long row = m0 + rowB + m*16 + fq*4 + j;
        #pragma unroll
        for (int n = 0; n < NF; n++){
          int colL = n0 + colB + n*16 + fr;
          float v = acc[m][n][j] + bias[colL];
          if (COLSCALE) v *= gamma[colL];
          if (ACT == 1) v = 0.5f * v * (1.0f + erff(v * 0.70710678118654752f));
          int colS = colL + colOff;
          C[(long)(colS>>4)*SB16 + row*16 + (colS&15)] = f2bf(v);
        }
      }
    }
  } else {
    #pragma unroll
    for (int m = 0; m < MF; m++){
      #pragma unroll
      for (int j = 0; j < 4; j++){
        int rt = rowB + m*16 + fq*4 + j;
        long tok = m0 + rt;
        float vv[NF];
        float s1 = 0.f, s2 = 0.f;
        #pragma unroll
        for (int n = 0; n < NF; n++){
          int col = n*16 + fr;
          float v = acc[m][n][j] + bias[col];
          if (EPI == 2){
            v = 1.0f / (1.0f + expf(-v));
            float idv = bf2f(((const short*)g_cat)[(long)n*SB16 + tok*16 + fr]);
            float lmv = bf2f(((const short*)g_cat)[(long)(n+8)*SB16 + tok*16 + fr]);
            v = v*idv + (1.0f - v)*lmv;
          } else {
            v += bf2f(((const short*)g_xb)[(long)n*SB16 + tok*16 + fr]);
          }
          vv[n] = v; s1 += v; s2 += v*v;
        }
        #pragma unroll
        for (int off = 1; off < 16; off <<= 1){
          s1 += __shfl_xor(s1, off); s2 += __shfl_xor(s2, off);
        }
        float mu = s1 * (1.f/128.f);
        float var = s2 * (1.f/128.f) - mu*mu;
        float rstd = rsqrtf(var + 1e-12f);
        #pragma unroll
        for (int n = 0; n < NF; n++){
          int col = n*16 + fr;
          float o = (vv[n] - mu)*rstd*lnG[col] + lnB[col];
          ((short*)g_xb)[(long)n*SB16 + tok*16 + fr] = f2bf(o);
        }
      }
    }
  }
}

// ---------------- named GEMM wrappers ---------------------------------------
__global__ __launch_bounds__(256) void kg_llm(const float* llm_emb, const float* b_map, const int* ids){
  mgemm_body<0,0,true,false>(nullptr, llm_emb, 768, (const short*)g_Wmap, 128L*16,
                             b_map, nullptr, ids, (short*)g_cat, 0, 128, 768, nullptr, nullptr);
}
__global__ __launch_bounds__(256) void kg_g1(const float* bg1){
  mgemm_body<1,0,false,false>((const short*)g_cat, nullptr, 0, (const short*)g_Wg1, 256L*16,
                              bg1, nullptr, nullptr, (short*)g_g1, SB16, 0, 256, nullptr, nullptr);
}
__global__ __launch_bounds__(256) void kg_gate(const float* bg2, const float* ln0g, const float* ln0b){
  mgemm_body<0,2,false,false>((const short*)g_g1, nullptr, 0, (const short*)g_Wg2, 128L*16,
                              bg2, nullptr, nullptr, nullptr, SB16, 0, 256, ln0g, ln0b);
}
__global__ __launch_bounds__(256) void kg_h(int l){
  mgemm_body<0,0,false,true>((const short*)g_xb, nullptr, 0,
                             (const short*)g_Wincat + (long)l*65536, 512L*16,
                             g_bincat + l*512, g_gamma2 + l*512, nullptr, (short*)g_h,
                             SB16, 0, 128, nullptr, nullptr);
}
__global__ __launch_bounds__(256) void kg_out(int l, const float* bout, const float* g, const float* b){
  mgemm_body<0,1,false,false>((const short*)g_h, nullptr, 0,
                              (const short*)g_Woutcat + (long)l*65536, 128L*16,
                              bout, nullptr, nullptr, nullptr, SB16, 0, 512, g, b);
}
__global__ __launch_bounds__(256) void kg_ff1(int l, const float* bff1){
  mgemm_body<1,0,false,false>((const short*)g_xb, nullptr, 0,
                              (const short*)g_Wff1 + (long)l*65536, 512L*16,
                              bff1, nullptr, nullptr, (short*)g_ffh, SB16, 0, 128, nullptr, nullptr);
}
__global__ __launch_bounds__(256) void kg_ff2(int l, const float* bff2, const float* g, const float* b){
  mgemm_body<0,1,false,false>((const short*)g_ffh, nullptr, 0,
                              (const short*)g_Wff2 + (long)l*65536, 128L*16,
                              bff2, nullptr, nullptr, nullptr, SB16, 0, 512, g, b);
}

// ---------------- blocked LRU scan (token-major I/O, padded in LDS) ---------
__global__ __launch_bounds__(256) void k_scan(int l){
  __shared__ __align__(16) float sre[CL*16];
  __shared__ __align__(16) float sim[CL*16];
  __shared__ float smask[CL];
  int b = blockIdx.y, ch = blockIdx.x;  // ch 0..15
  int tid = threadIdx.x;
  short* Hre = (short*)g_h + (long)ch*SB16 + (long)b*CS*16;
  short* Him = (short*)g_h + (long)(ch+16)*SB16 + (long)b*CS*16;
  smask[tid] = g_mask[b*CL + tid];
  for (int q = tid; q < 224; q += 256){    // zero pad rows 0..55 (56*16/4)
    ((float4*)sre)[q] = make_float4(0.f,0.f,0.f,0.f);
    ((float4*)sim)[q] = make_float4(0.f,0.f,0.f,0.f);
  }
  for (int q = tid; q < 400; q += 256){    // 200 tokens * 16 / 8
    bf16x8 r8 = ((const bf16x8*)Hre)[q];
    bf16x8 i8 = ((const bf16x8*)Him)[q];
    int base = 896 + q*8;
    #pragma unroll
    for (int k = 0; k < 8; k++){ sre[base+k] = bf2f(r8[k]); sim[base+k] = bf2f(i8[k]); }
  }
  __syncthreads();
  const float2* lam = g_lam + ((long)l*16 + ch)*2048;
  const int dl = tid & 15, u0 = tid >> 4;
  for (int i = 1; i <= 8; i++){
    int hl = 1 << (i-1);
    #pragma unroll
    for (int k = 0; k < 8; k++){
      int u = u0 + k*16;
      int blkI = u >> (i-1), j = u & (hl-1);
      int p = (blkI << i) + hl - 1;
      int tt = p + 1 + j;
      float mv = smask[p];
      float2 L = lam[j*16 + dl];
      float hr = sre[p*16+dl], hi = sim[p*16+dl];
      sre[tt*16+dl] += (L.x*hr - L.y*hi) * mv;
      sim[tt*16+dl] += (L.x*hi + L.y*hr) * mv;
    }
    __syncthreads();
  }
  for (int q = tid; q < 400; q += 256){
    int base = 896 + q*8;
    bf16x8 r8, i8;
    #pragma unroll
    for (int k = 0; k < 8; k++){ r8[k] = f2bf(sre[base+k]); i8[k] = f2bf(sim[base+k]); }
    ((bf16x8*)Hre)[q] = r8;
    ((bf16x8*)Him)[q] = i8;
  }
}

// ---------------- final copy (bf16 blocked -> f32 row-major) ----------------
__global__ void k_copy_out(float* __restrict__ out){
  int i = blockIdx.x*256 + threadIdx.x;  // over CBS*CH
  int tok = i >> 7, c = i & (CH-1);
  out[i] = bf2f(((const short*)g_xb)[(long)(c>>4)*SB16 + (long)tok*16 + (c&15)]);
}

// ---------------------------------------------------------------------------
extern "C" void kernel_launch(void* const* d_in, const int* in_sizes, int n_in,
                              void* d_out, int out_size, void* d_ws, size_t ws_size,
                              hipStream_t stream) {
  const int*   ids       = (const int*)  d_in[0];
  const float* item_emb  = (const float*)d_in[1];
  const float* llm_emb   = (const float*)d_in[2];
  const float* W_map     = (const float*)d_in[3];
  const float* b_map     = (const float*)d_in[4];
  const float* Wg1       = (const float*)d_in[5];
  const float* bg1       = (const float*)d_in[6];
  const float* Wg2       = (const float*)d_in[7];
  const float* bg2       = (const float*)d_in[8];
  const float* ln0_g     = (const float*)d_in[9];
  const float* ln0_b     = (const float*)d_in[10];
  const float* params_log= (const float*)d_in[11];
  const float* Win_re    = (const float*)d_in[12];
  const float* Win_im    = (const float*)d_in[13];
  const float* bin_re    = (const float*)d_in[14];
  const float* bin_im    = (const float*)d_in[15];
  const float* Wout_re   = (const float*)d_in[16];
  const float* Wout_im   = (const float*)d_in[17];
  const float* bout_re   = (const float*)d_in[18];
  const float* ln1_g     = (const float*)d_in[20];
  const float* ln1_b     = (const float*)d_in[21];
  const float* Wff1      = (const float*)d_in[22];
  const float* bff1      = (const float*)d_in[23];
  const float* Wff2      = (const float*)d_in[24];
  const float* bff2      = (const float*)d_in[25];
  const float* ln2_g     = (const float*)d_in[26];
  const float* ln2_b     = (const float*)d_in[27];
  float* out = (float*)d_out;

  dim3 blk(256);

  k_wcvt_all<<<2816, blk, 0, stream>>>(W_map, Wg1, Wg2, Win_re, Win_im,
                                       Wout_re, Wout_im, Wff1, Wff2);
  k_prep<<<2, 256, 0, stream>>>(params_log, bin_re, bin_im);
  k_mask<<<CB, CL, 0, stream>>>(ids);
  k_gather_ids<<<CBS, CH, 0, stream>>>(ids, item_emb);

  kg_llm<<<dim3(400,1), blk, 0, stream>>>(llm_emb, b_map, ids);
  kg_g1 <<<dim3(400,2), blk, 0, stream>>>(bg1);
  kg_gate<<<dim3(400,1), blk, 0, stream>>>(bg2, ln0_g, ln0_b);

  for (int l = 0; l < 2; l++){
    kg_h  <<<dim3(400,4), blk, 0, stream>>>(l);
    k_scan<<<dim3(16,CB), blk, 0, stream>>>(l);
    kg_out<<<dim3(400,1), blk, 0, stream>>>(l, bout_re + l*128, ln1_g + l*128, ln1_b + l*128);
    kg_ff1<<<dim3(400,4), blk, 0, stream>>>(l, bff1 + l*512);
    kg_ff2<<<dim3(400,1), blk, 0, stream>>>(l, bff2 + l*128, ln2_g + l*128, ln2_b + l*128);
  }

  k_copy_out<<<(CBS*CH)/256, blk, 0, stream>>>(out);
}

// Round 6
// 440.223 us; speedup vs baseline: 1.7473x; 1.0003x over previous
//
#include <hip/hip_runtime.h>
#include <hip/hip_bf16.h>

#define CB 256       // batch
#define CS 200       // seq
#define CH 128       // H
#define CH2 256      // 2H
#define CL 256       // padded scan length
#define CPAD 56
#define CBS (CB*CS)  // 51200 real tokens

typedef __attribute__((ext_vector_type(8))) short bf16x8;
typedef __attribute__((ext_vector_type(4))) float f32x4;

#define SB16 ((long)CBS*16)   // 16-channel chunk stride (token-major)

// ---------------- static device buffers ------------------------------------
// blocked bf16 activations: elem(c,tok) at (c>>4)*SB16 + tok*16 + (c&15)
__device__ __align__(16) __hip_bfloat16 g_cat [(size_t)CBS*256];
__device__ __align__(16) __hip_bfloat16 g_g1  [(size_t)CBS*256];
__device__ __align__(16) __hip_bfloat16 g_xb  [(size_t)CBS*128]; // residual
__device__ __align__(16) __hip_bfloat16 g_h   [(size_t)CBS*512]; // [re|im]
__device__ __align__(16) __hip_bfloat16 g_ffh [(size_t)CBS*512];
__device__ float g_mask[CB*CL];
__device__ float g_gamma2[2*512];
__device__ float g_bincat[2*512];
__device__ float2 g_lam[2*16*128*16];  // [l][ch16][j][dl]
// bf16 weights, 16-K-chunk blocked: elem(r,c) at (c>>4)*(N*16) + r*16 + (c&15)
__device__ __align__(16) __hip_bfloat16 g_Wmap  [128*768];
__device__ __align__(16) __hip_bfloat16 g_Wg1   [256*256];
__device__ __align__(16) __hip_bfloat16 g_Wg2   [128*256];
__device__ __align__(16) __hip_bfloat16 g_Wincat[2*512*128];
__device__ __align__(16) __hip_bfloat16 g_Woutcat[2*128*512];
__device__ __align__(16) __hip_bfloat16 g_Wff1  [2*512*128];
__device__ __align__(16) __hip_bfloat16 g_Wff2  [2*128*512];

__device__ __forceinline__ short f2bf(float f){
  unsigned u = __float_as_uint(f);
  unsigned r = (u + 0x7fffu + ((u>>16)&1u)) >> 16;
  return (short)r;
}
__device__ __forceinline__ float bf2f(short s){
  return __uint_as_float(((unsigned)(unsigned short)s) << 16);
}

typedef const __attribute__((address_space(1))) void* gas1;
typedef __attribute__((address_space(3))) void* las3;
__device__ __forceinline__ void gl16(const void* g, void* l){
  __builtin_amdgcn_global_load_lds((gas1)g, (las3)l, 16, 0, 0);
}

// ---------------- merged setup: weight convert + mask + lambda prep ---------
__device__ __forceinline__ void wblk(__hip_bfloat16* dst, int N, int K, int i, float v){
  int r = i / K, c = i - r*K;
  ((short*)dst)[(long)(c>>4)*((long)N*16) + (long)r*16 + (c&15)] = f2bf(v);
}
__global__ void k_setup(const float* __restrict__ W_map, const float* __restrict__ Wg1,
                        const float* __restrict__ Wg2,
                        const float* __restrict__ Win_re, const float* __restrict__ Win_im,
                        const float* __restrict__ Wout_re, const float* __restrict__ Wout_im,
                        const float* __restrict__ Wff1, const float* __restrict__ Wff2,
                        const int* __restrict__ ids,
                        const float* __restrict__ pl,
                        const float* __restrict__ binre, const float* __restrict__ binim){
  int bi = blockIdx.x, t = threadIdx.x;
  if (bi < 2816){
    int i = bi*256 + t;
    if (i < 98304){ wblk(g_Wmap, 128, 768, i, W_map[i]); return; }
    i -= 98304;
    if (i < 65536){ wblk(g_Wg1, 256, 256, i, Wg1[i]); return; }
    i -= 65536;
    if (i < 32768){ wblk(g_Wg2, 128, 256, i, Wg2[i]); return; }
    i -= 32768;
    int l = i / 262144; i -= l*262144;
    if (i < 32768){ wblk(g_Wincat + (long)l*65536, 512, 128, i,       Win_re[(long)l*32768 + i]); return; }
    i -= 32768;
    if (i < 32768){ wblk(g_Wincat + (long)l*65536, 512, 128, i+32768, Win_im[(long)l*32768 + i]); return; }
    i -= 32768;
    if (i < 65536){
      int r = i >> 9, c = i & 511;
      float v = (c < 256) ? Wout_re[(long)l*32768 + r*256 + c]
                          : -Wout_im[(long)l*32768 + r*256 + (c-256)];
      wblk(g_Woutcat + (long)l*65536, 128, 512, i, v); return;
    }
    i -= 65536;
    if (i < 65536){ wblk(g_Wff1 + (long)l*65536, 512, 128, i, Wff1[(long)l*65536 + i]); return; }
    i -= 65536;
    wblk(g_Wff2 + (long)l*65536, 128, 512, i, Wff2[(long)l*65536 + i]);
    return;
  }
  if (bi < 3072){
    int b = bi - 2816;
    float m = 0.f;
    if (t >= CPAD) m = (ids[b*CS + (t - CPAD)] > 0) ? 1.f : 0.f;
    g_mask[b*CL + t] = m;
    return;
  }
  {
    int l = bi - 3072, d = t;
    float nu = expf(pl[(l*3+0)*CH2 + d]);
    float th = expf(pl[(l*3+1)*CH2 + d]);
    float gm = expf(pl[(l*3+2)*CH2 + d]);
    g_gamma2[l*512 + d] = gm;       g_gamma2[l*512 + d + 256] = gm;
    g_bincat[l*512 + d] = binre[l*256 + d];
    g_bincat[l*512 + d + 256] = binim[l*256 + d];
    float r = expf(-nu);
    float lre = r*cosf(th), lim = r*sinf(th);
    float pr = lre, pi = lim;
    long base = ((long)l*16 + (d>>4))*2048 + (d&15);
    for (int k = 0; k < 128; k++){
      g_lam[base + (long)k*16] = make_float2(pr, pi);
      float nr = pr*lre - pi*lim;
      float ni = pr*lim + pi*lre;
      pr = nr; pi = ni;
    }
  }
}

// ---------------- item-embedding gather (vectorized, blocked-16) ------------
__global__ __launch_bounds__(256) void k_gather_ids(const int* __restrict__ ids,
                                                    const float* __restrict__ item_emb){
  int t = threadIdx.x;
  int tok = blockIdx.x*16 + (t>>4);
  int cg = t & 15;                    // 16 groups of 8 channels
  int id = ids[tok];
  const float* p = item_emb + (size_t)id*128 + cg*8;
  float4 x0 = *(const float4*)p;
  float4 x1 = *(const float4*)(p + 4);
  bf16x8 v;
  v[0]=f2bf(x0.x); v[1]=f2bf(x0.y); v[2]=f2bf(x0.z); v[3]=f2bf(x0.w);
  v[4]=f2bf(x1.x); v[5]=f2bf(x1.y); v[6]=f2bf(x1.z); v[7]=f2bf(x1.w);
  *(bf16x8*)((short*)g_cat + (long)(cg>>1)*SB16 + (long)tok*16 + (cg&1)*8) = v;
}

// ---------------- MFMA GEMM body, BK=64, global_load_lds staging ------------
// TM=128: EPI0 only, 2x2 waves (MF=4,NF=4).
// TM=64:  EPI0 2x2 waves (MF=2,NF=4); EPI1/2 4x1 waves (MF=1,NF=8).
// EPI1: LN(v + bias + xb) -> xb.  EPI2: sigmoid-mix-LN0 -> xb.
template<int TM, int ACT, int EPI, bool GATHER, bool COLSCALE>
__device__ __forceinline__ void mgemm_body(
    const short* __restrict__ A, const float* __restrict__ Af32, int ldaF,
    const short* __restrict__ W, long wBlk,
    const float* __restrict__ bias, const float* __restrict__ gamma,
    const int* __restrict__ gidx, short* __restrict__ C,
    long aBlk, int colOff, int K,
    const float* __restrict__ lnG, const float* __restrict__ lnB)
{
  constexpr int ACH = TM*32;                 // bytes per 16-k A chunk
  __shared__ __align__(16) char lA[TM*128];
  __shared__ __align__(16) char lB[16384];
  constexpr int MF = (EPI==0) ? (TM/32) : 1;
  constexpr int NF = (EPI==0) ? 4 : 8;
  const int t = threadIdx.x;
  const int m0 = blockIdx.x*TM, n0 = blockIdx.y*128;
  const int lane = t & 63, wv = t >> 6;
  const int wr = (EPI==0)?(wv>>1):wv;
  const int wc = (EPI==0)?(wv&1):0;
  const int fr = lane & 15, fq = lane >> 4;
  const int rowB = (EPI==0) ? wr*(TM/2) : wv*16;
  const int colB = wc*64;

  long gr0 = 0, gr1 = 0;
  if (GATHER){ gr0 = gidx[m0 + (t>>3)]; gr1 = gidx[m0 + (t>>3) + 32]; }

  f32x4 acc[MF][NF] = {};

  for (int k0 = 0; k0 < K; k0 += 64){
    if (TM == 128){
      #pragma unroll
      for (int cc = 0; cc < 4; cc++){
        const short* gp = A + (long)((k0>>4)+cc)*aBlk + (long)(m0 + wv*32)*16 + (lane<<3);
        gl16(gp, lA + cc*4096 + wv*1024);
      }
      #pragma unroll
      for (int cc = 0; cc < 4; cc++){
        const short* gp = W + (long)((k0>>4)+cc)*wBlk + (long)(n0 + wv*32)*16 + (lane<<3);
        gl16(gp, lB + cc*4096 + wv*1024);
      }
    } else {
      if (GATHER){
        #pragma unroll
        for (int rep = 0; rep < 2; rep++){
          int slot = t + rep*256;
          int row = slot>>3, cc = (slot>>1)&3, half = slot&1;
          long ar = rep ? gr1 : gr0;
          const float* p = Af32 + ar*(long)ldaF + k0 + cc*16 + half*8;
          float4 x0 = *(const float4*)p;
          float4 x1 = *(const float4*)(p + 4);
          bf16x8 v;
          v[0]=f2bf(x0.x); v[1]=f2bf(x0.y); v[2]=f2bf(x0.z); v[3]=f2bf(x0.w);
          v[4]=f2bf(x1.x); v[5]=f2bf(x1.y); v[6]=f2bf(x1.z); v[7]=f2bf(x1.w);
          *(bf16x8*)(lA + cc*2048 + row*32 + half*16) = v;
        }
      } else {
        #pragma unroll
        for (int p = 0; p < 2; p++){
          const short* gp = A + (long)((k0>>4)+wv)*aBlk + (long)(m0 + p*32 + (lane>>1))*16 + (lane&1)*8;
          gl16(gp, lA + wv*2048 + p*1024);
        }
      }
      #pragma unroll
      for (int p = 0; p < 4; p++){
        const short* gp = W + (long)((k0>>4)+wv)*wBlk + (long)(n0 + p*32 + (lane>>1))*16 + (lane&1)*8;
        gl16(gp, lB + wv*4096 + p*1024);
      }
    }
    __syncthreads();
    #pragma unroll
    for (int s = 0; s < 2; s++){
      const int cc = s*2 + (fq>>1);
      bf16x8 af[MF], bw[NF];
      #pragma unroll
      for (int m = 0; m < MF; m++)
        af[m] = *(const bf16x8*)(lA + cc*ACH + (rowB + m*16 + fr)*32 + (fq&1)*16);
      #pragma unroll
      for (int n = 0; n < NF; n++)
        bw[n] = *(const bf16x8*)(lB + cc*4096 + (colB + n*16 + fr)*32 + (fq&1)*16);
      #pragma unroll
      for (int m = 0; m < MF; m++)
        #pragma unroll
        for (int n = 0; n < NF; n++)
          acc[m][n] = __builtin_amdgcn_mfma_f32_16x16x32_bf16(af[m], bw[n], acc[m][n], 0, 0, 0);
    }
    __syncthreads();
  }

  if (EPI == 0){
    #pragma unroll
    for (int m = 0; m < MF; m++){
      #pragma unroll
      for (int j = 0; j < 4; j++){
        long row = m0 + rowB + m*16 + fq*4 + j;
        #pragma unroll
        for (int n = 0; n < NF; n++){
          int colL = n0 + colB + n*16 + fr;
          float v = acc[m][n][j] + bias[colL];
          if (COLSCALE) v *= gamma[colL];
          if (ACT == 1) v = 0.5f * v * (1.0f + erff(v * 0.70710678118654752f));
          int colS = colL + colOff;
          C[(long)(colS>>4)*SB16 + row*16 + (colS&15)] = f2bf(v);
        }
      }
    }
  } else {
    #pragma unroll
    for (int j = 0; j < 4; j++){
      int rt = rowB + fq*4 + j;
      long tok = m0 + rt;
      float vv[NF];
      float s1 = 0.f, s2 = 0.f;
      #pragma unroll
      for (int n = 0; n < NF; n++){
        int col = n*16 + fr;
        float v = acc[0][n][j] + bias[col];
        if (EPI == 2){
          v = 1.0f / (1.0f + expf(-v));
          float idv = bf2f(((const short*)g_cat)[(long)n*SB16 + tok*16 + fr]);
          float lmv = bf2f(((const short*)g_cat)[(long)(n+8)*SB16 + tok*16 + fr]);
          v = v*idv + (1.0f - v)*lmv;
        } else {
          v += bf2f(((const short*)g_xb)[(long)n*SB16 + tok*16 + fr]);
        }
        vv[n] = v; s1 += v; s2 += v*v;
      }
      #pragma unroll
      for (int off = 1; off < 16; off <<= 1){
        s1 += __shfl_xor(s1, off); s2 += __shfl_xor(s2, off);
      }
      float mu = s1 * (1.f/128.f);
      float var = s2 * (1.f/128.f) - mu*mu;
      float rstd = rsqrtf(var + 1e-12f);
      #pragma unroll
      for (int n = 0; n < NF; n++){
        int col = n*16 + fr;
        float o = (vv[n] - mu)*rstd*lnG[col] + lnB[col];
        ((short*)g_xb)[(long)n*SB16 + tok*16 + fr] = f2bf(o);
      }
    }
  }
}

// ---------------- named GEMM wrappers ---------------------------------------
__global__ __launch_bounds__(256) void kg_llm(const float* llm_emb, const float* b_map, const int* ids){
  mgemm_body<64,0,0,true,false>(nullptr, llm_emb, 768, (const short*)g_Wmap, 128L*16,
                                b_map, nullptr, ids, (short*)g_cat, 0, 128, 768, nullptr, nullptr);
}
__global__ __launch_bounds__(256) void kg_g1(const float* bg1){
  mgemm_body<64,1,0,false,false>((const short*)g_cat, nullptr, 0, (const short*)g_Wg1, 256L*16,
                                 bg1, nullptr, nullptr, (short*)g_g1, SB16, 0, 256, nullptr, nullptr);
}
__global__ __launch_bounds__(256) void kg_gate(const float* bg2, const float* ln0g, const float* ln0b){
  mgemm_body<64,0,2,false,false>((const short*)g_g1, nullptr, 0, (const short*)g_Wg2, 128L*16,
                                 bg2, nullptr, nullptr, nullptr, SB16, 0, 256, ln0g, ln0b);
}
__global__ __launch_bounds__(256) void kg_h(int l){
  mgemm_body<128,0,0,false,true>((const short*)g_xb, nullptr, 0,
                                 (const short*)g_Wincat + (long)l*65536, 512L*16,
                                 g_bincat + l*512, g_gamma2 + l*512, nullptr, (short*)g_h,
                                 SB16, 0, 128, nullptr, nullptr);
}
__global__ __launch_bounds__(256) void kg_out(int l, const float* bout, const float* g, const float* b){
  mgemm_body<64,0,1,false,false>((const short*)g_h, nullptr, 0,
                                 (const short*)g_Woutcat + (long)l*65536, 128L*16,
                                 bout, nullptr, nullptr, nullptr, SB16, 0, 512, g, b);
}
__global__ __launch_bounds__(256) void kg_ff1(int l, const float* bff1){
  mgemm_body<128,1,0,false,false>((const short*)g_xb, nullptr, 0,
                                  (const short*)g_Wff1 + (long)l*65536, 512L*16,
                                  bff1, nullptr, nullptr, (short*)g_ffh, SB16, 0, 128, nullptr, nullptr);
}
__global__ __launch_bounds__(256) void kg_ff2(int l, const float* bff2, const float* g, const float* b){
  mgemm_body<64,0,1,false,false>((const short*)g_ffh, nullptr, 0,
                                 (const short*)g_Wff2 + (long)l*65536, 128L*16,
                                 bff2, nullptr, nullptr, nullptr, SB16, 0, 512, g, b);
}

// ---------------- blocked LRU scan (token-major I/O, padded in LDS) ---------
__global__ __launch_bounds__(256) void k_scan(int l){
  __shared__ __align__(16) float sre[CL*16];
  __shared__ __align__(16) float sim[CL*16];
  __shared__ float smask[CL];
  int b = blockIdx.y, ch = blockIdx.x;  // ch 0..15
  int tid = threadIdx.x;
  short* Hre = (short*)g_h + (long)ch*SB16 + (long)b*CS*16;
  short* Him = (short*)g_h + (long)(ch+16)*SB16 + (long)b*CS*16;
  smask[tid] = g_mask[b*CL + tid];
  for (int q = tid; q < 224; q += 256){    // zero pad rows 0..55
    ((float4*)sre)[q] = make_float4(0.f,0.f,0.f,0.f);
    ((float4*)sim)[q] = make_float4(0.f,0.f,0.f,0.f);
  }
  for (int q = tid; q < 400; q += 256){    // 200 tokens * 16 / 8
    bf16x8 r8 = ((const bf16x8*)Hre)[q];
    bf16x8 i8 = ((const bf16x8*)Him)[q];
    int base = 896 + q*8;
    #pragma unroll
    for (int k = 0; k < 8; k++){ sre[base+k] = bf2f(r8[k]); sim[base+k] = bf2f(i8[k]); }
  }
  __syncthreads();
  const float2* lam = g_lam + ((long)l*16 + ch)*2048;
  const int dl = tid & 15, u0 = tid >> 4;
  for (int i = 1; i <= 8; i++){
    int hl = 1 << (i-1);
    #pragma unroll
    for (int k = 0; k < 8; k++){
      int u = u0 + k*16;
      int blkI = u >> (i-1), j = u & (hl-1);
      int p = (blkI << i) + hl - 1;
      int tt = p + 1 + j;
      float mv = smask[p];
      float2 L = lam[j*16 + dl];
      float hr = sre[p*16+dl], hi = sim[p*16+dl];
      sre[tt*16+dl] += (L.x*hr - L.y*hi) * mv;
      sim[tt*16+dl] += (L.x*hi + L.y*hr) * mv;
    }
    __syncthreads();
  }
  for (int q = tid; q < 400; q += 256){
    int base = 896 + q*8;
    bf16x8 r8, i8;
    #pragma unroll
    for (int k = 0; k < 8; k++){ r8[k] = f2bf(sre[base+k]); i8[k] = f2bf(sim[base+k]); }
    ((bf16x8*)Hre)[q] = r8;
    ((bf16x8*)Him)[q] = i8;
  }
}

// ---------------- final copy (bf16 blocked -> f32 row-major, float4) --------
__global__ __launch_bounds__(256) void k_copy_out(float* __restrict__ out){
  int i = blockIdx.x*256 + threadIdx.x;  // quad index over CBS*CH/4
  int base = i*4;
  int tok = base >> 7, c = base & 127;
  short4 s4 = *(const short4*)((const short*)g_xb + (long)(c>>4)*SB16 + (long)tok*16 + (c&15));
  *(float4*)(out + base) = make_float4(bf2f(s4.x), bf2f(s4.y), bf2f(s4.z), bf2f(s4.w));
}

// ---------------------------------------------------------------------------
extern "C" void kernel_launch(void* const* d_in, const int* in_sizes, int n_in,
                              void* d_out, int out_size, void* d_ws, size_t ws_size,
                              hipStream_t stream) {
  const int*   ids       = (const int*)  d_in[0];
  const float* item_emb  = (const float*)d_in[1];
  const float* llm_emb   = (const float*)d_in[2];
  const float* W_map     = (const float*)d_in[3];
  const float* b_map     = (const float*)d_in[4];
  const float* Wg1       = (const float*)d_in[5];
  const float* bg1       = (const float*)d_in[6];
  const float* Wg2       = (const float*)d_in[7];
  const float* bg2       = (const float*)d_in[8];
  const float* ln0_g     = (const float*)d_in[9];
  const float* ln0_b     = (const float*)d_in[10];
  const float* params_log= (const float*)d_in[11];
  const float* Win_re    = (const float*)d_in[12];
  const float* Win_im    = (const float*)d_in[13];
  const float* bin_re    = (const float*)d_in[14];
  const float* bin_im    = (const float*)d_in[15];
  const float* Wout_re   = (const float*)d_in[16];
  const float* Wout_im   = (const float*)d_in[17];
  const float* bout_re   = (const float*)d_in[18];
  const float* ln1_g     = (const float*)d_in[20];
  const float* ln1_b     = (const float*)d_in[21];
  const float* Wff1      = (const float*)d_in[22];
  const float* bff1      = (const float*)d_in[23];
  const float* Wff2      = (const float*)d_in[24];
  const float* bff2      = (const float*)d_in[25];
  const float* ln2_g     = (const float*)d_in[26];
  const float* ln2_b     = (const float*)d_in[27];
  float* out = (float*)d_out;

  dim3 blk(256);

  k_setup<<<3074, blk, 0, stream>>>(W_map, Wg1, Wg2, Win_re, Win_im,
                                    Wout_re, Wout_im, Wff1, Wff2,
                                    ids, params_log, bin_re, bin_im);
  k_gather_ids<<<CBS/16, blk, 0, stream>>>(ids, item_emb);

  kg_llm <<<dim3(800,1), blk, 0, stream>>>(llm_emb, b_map, ids);
  kg_g1  <<<dim3(800,2), blk, 0, stream>>>(bg1);
  kg_gate<<<dim3(800,1), blk, 0, stream>>>(bg2, ln0_g, ln0_b);

  for (int l = 0; l < 2; l++){
    kg_h  <<<dim3(400,4), blk, 0, stream>>>(l);
    k_scan<<<dim3(16,CB), blk, 0, stream>>>(l);
    kg_out<<<dim3(800,1), blk, 0, stream>>>(l, bout_re + l*128, ln1_g + l*128, ln1_b + l*128);
    kg_ff1<<<dim3(400,4), blk, 0, stream>>>(l, bff1 + l*512);
    kg_ff2<<<dim3(800,1), blk, 0, stream>>>(l, bff2 + l*128, ln2_g + l*128, ln2_b + l*128);
  }

  k_copy_out<<<(CBS*CH)/1024, blk, 0, stream>>>(out);
}